// Round 9
// baseline (169.166 us; speedup 1.0000x reference)
//
#include <hip/hip_runtime.h>
#include <math.h>

#define B_ 4
#define S_ 1024
#define D_ 1024
#define H_ 16
#define DK_ 64

typedef short bf16x8 __attribute__((ext_vector_type(8)));
typedef float f32x4 __attribute__((ext_vector_type(4)));

__device__ __forceinline__ unsigned short f2bf(float f) {
    unsigned int u = __float_as_uint(f);
    u = (u + 0x7FFFu + ((u >> 16) & 1u)) >> 16;  // RNE
    return (unsigned short)u;
}

__device__ __forceinline__ float exp2_fast(float x) {
#if __has_builtin(__builtin_amdgcn_exp2f)
    return __builtin_amdgcn_exp2f(x);
#else
    return exp2f(x);
#endif
}

// single-instruction pack: lo -> bits[15:0], hi -> bits[31:16] (bf16 RNE)
__device__ __forceinline__ int cvt_pk_bf16(float lo, float hi) {
    int r;
    asm("v_cvt_pk_bf16_f32 %0, %1, %2" : "=v"(r) : "v"(lo), "v"(hi));
    return r;
}

// async 16B/lane global -> LDS (lands at lds_base + lane*16)
__device__ __forceinline__ void gl2lds16(const void* g, void* l) {
    typedef unsigned int u32;
    auto gp = (const __attribute__((address_space(1))) u32*)(unsigned long long)g;
    auto lp = (__attribute__((address_space(3))) u32*)(unsigned int)(unsigned long long)l;
    __builtin_amdgcn_global_load_lds(gp, lp, 16, 0, 0);
}

#define LOG2E 1.44269504f
#define BIAS_OFF 20.0f

// ---------------------------------------------------------------------------
// fused conversion kernel: blocks [0,4096) convert x -> bf16;
// blocks [4096,8192) transpose+convert the 4 weight matrices -> Wts
// ---------------------------------------------------------------------------
__global__ __launch_bounds__(256) void conv_all(
    const float* __restrict__ x,
    const float* __restrict__ W0, const float* __restrict__ W1,
    const float* __restrict__ W2, const float* __restrict__ W3,
    unsigned short* __restrict__ xb, unsigned short* __restrict__ Wts)
{
    __shared__ float T[32][33];
    const int t = threadIdx.x;
    const int bid = blockIdx.x;

    if (bid < 4096) {
        int i = (bid * 256 + t) * 4;
        float4 v = *(const float4*)&x[i];
        ushort4 o;
        o.x = f2bf(v.x); o.y = f2bf(v.y); o.z = f2bf(v.z); o.w = f2bf(v.w);
        *(ushort4*)&xb[i] = o;
        return;
    }
    int tile = bid - 4096;
    const int mat = tile >> 10;
    tile &= 1023;
    const float* W = (mat == 0) ? W0 : (mat == 1) ? W1 : (mat == 2) ? W2 : W3;
    unsigned short* Wt = Wts + (size_t)mat * 1048576;
    const int k0 = (tile >> 5) * 32, n0 = (tile & 31) * 32;
    {
        int r = t >> 3, c4 = (t & 7) * 4;
        float4 v = *(const float4*)&W[(size_t)(k0 + r) * D_ + n0 + c4];
        T[r][c4 + 0] = v.x; T[r][c4 + 1] = v.y; T[r][c4 + 2] = v.z; T[r][c4 + 3] = v.w;
    }
    __syncthreads();
    {
        int rn = t >> 3, c4 = (t & 7) * 4;
        ushort4 o;
        o.x = f2bf(T[c4 + 0][rn]); o.y = f2bf(T[c4 + 1][rn]);
        o.z = f2bf(T[c4 + 2][rn]); o.w = f2bf(T[c4 + 3][rn]);
        *(ushort4*)&Wt[(size_t)(n0 + rn) * D_ + k0 + c4] = o;
    }
}

// ---------------------------------------------------------------------------
// bf16 MFMA GEMM 128x128, BK=32. Double-buffered LDS with single barrier
// per K-step: issue next K-step's global_load_lds right after the barrier,
// compute current buffer. LDS 32 KB; grid 768 = 3/CU, XCD-swizzled.
// ---------------------------------------------------------------------------
__global__ __launch_bounds__(256) void gemm_qkv(
    const unsigned short* __restrict__ xb,
    const unsigned short* __restrict__ Wts,
    unsigned short* __restrict__ Qb, unsigned short* __restrict__ Kb,
    unsigned short* __restrict__ Vtb)
{
    const int bid = blockIdx.x;
    const int by = bid & 31;          // x row-tile: XCD residue = by%8
    const int t_ = bid >> 5;          // 0..23
    const int z = t_ >> 3;            // 0..2 (Wq/Wk/Wv)
    const int bx = t_ & 7;            // W col-tile
    const unsigned short* Bt = Wts + (size_t)z * 1048576;

    __shared__ __align__(16) unsigned short Ast[2][128][32];
    __shared__ __align__(16) unsigned short Bst[2][128][32];

    const int tid = threadIdx.x;
    const int wave = tid >> 6, lane = tid & 63;
    const int quad = lane >> 4, l16 = lane & 15;
    const int wm = (wave & 1) * 64, wn = (wave >> 1) * 64;
    const int row0 = by * 128, col0 = bx * 128;
    const int lr = lane >> 2, lc = (lane & 3) * 8;

    f32x4 acc[4][4];
#pragma unroll
    for (int i = 0; i < 4; i++)
#pragma unroll
        for (int j = 0; j < 4; j++) acc[i][j] = 0;

    auto stage = [&](int sb, int k0) {
#pragma unroll
        for (int c = 0; c < 2; c++) {
            int m = wave * 32 + c * 16;
            gl2lds16(&xb[(size_t)(row0 + m + lr) * D_ + k0 + lc], &Ast[sb][m][0]);
            gl2lds16(&Bt[(size_t)(col0 + m + lr) * D_ + k0 + lc], &Bst[sb][m][0]);
        }
    };

    stage(0, 0);
    int db = 0;
    for (int k0 = 0; k0 < D_; k0 += 32) {
        // single barrier: drains this buffer's loads (issued one compute
        // phase ago for k0>0) and orders reuse of the other buffer.
        __syncthreads();
        if (k0 + 32 < D_) stage(db ^ 1, k0 + 32);

        bf16x8 af[4], bfr[4];
#pragma unroll
        for (int mt = 0; mt < 4; mt++)
            af[mt] = *(const bf16x8*)&Ast[db][wm + mt * 16 + l16][quad * 8];
#pragma unroll
        for (int nt = 0; nt < 4; nt++)
            bfr[nt] = *(const bf16x8*)&Bst[db][wn + nt * 16 + l16][quad * 8];
#pragma unroll
        for (int mt = 0; mt < 4; mt++)
#pragma unroll
            for (int nt = 0; nt < 4; nt++)
                acc[mt][nt] = __builtin_amdgcn_mfma_f32_16x16x32_bf16(
                    af[mt], bfr[nt], acc[mt][nt], 0, 0, 0);
        db ^= 1;
    }

    const float scale = (z == 0) ? LOG2E : 1.0f;
#pragma unroll
    for (int mt = 0; mt < 4; mt++)
#pragma unroll
        for (int nt = 0; nt < 4; nt++)
#pragma unroll
            for (int reg = 0; reg < 4; reg++) {
                int row = row0 + wm + mt * 16 + quad * 4 + reg;
                int col = col0 + wn + nt * 16 + l16;
                int b = row >> 10, s = row & 1023;
                int h = col >> 6, dk = col & 63;
                unsigned short v = f2bf(acc[mt][nt][reg] * scale);
                if (z == 0)      Qb[(((size_t)(b * H_ + h)) * S_ + s) * DK_ + dk] = v;
                else if (z == 1) Kb[(((size_t)(b * H_ + h)) * S_ + s) * DK_ + dk] = v;
                else             Vtb[(((size_t)(b * H_ + h)) * DK_ + dk) * S_ + s] = v;
            }
}

// ---------------------------------------------------------------------------
// Output GEMM: 64x128 tile, BK=32, double-buffered single-barrier prefetch.
// Flat grid 512, XCD-swizzled (bid%8==by%8).
// ---------------------------------------------------------------------------
__global__ __launch_bounds__(256) void gemm_out(
    const unsigned short* __restrict__ Ab,
    const unsigned short* __restrict__ Bt,
    float* __restrict__ out)
{
    const int bid = blockIdx.x;
    const int by = bid & 63;          // A row-tile: XCD residue = by%8
    const int bx = bid >> 6;          // 0..7

    __shared__ __align__(16) unsigned short Ast[2][64][32];
    __shared__ __align__(16) unsigned short Bst[2][128][32];

    const int tid = threadIdx.x;
    const int wave = tid >> 6, lane = tid & 63;
    const int quad = lane >> 4, l16 = lane & 15;
    const int wm = (wave & 1) * 32, wn = (wave >> 1) * 64;
    const int row0 = by * 64, col0 = bx * 128;
    const int lr = lane >> 2, lc = (lane & 3) * 8;

    f32x4 acc[2][4];
#pragma unroll
    for (int i = 0; i < 2; i++)
#pragma unroll
        for (int j = 0; j < 4; j++) acc[i][j] = 0;

    auto stage = [&](int sb, int k0) {
        gl2lds16(&Ab[(size_t)(row0 + wave * 16 + lr) * D_ + k0 + lc],
                 &Ast[sb][wave * 16][0]);
#pragma unroll
        for (int c = 0; c < 2; c++) {
            int m = (wave * 2 + c) * 16;
            gl2lds16(&Bt[(size_t)(col0 + m + lr) * D_ + k0 + lc], &Bst[sb][m][0]);
        }
    };

    stage(0, 0);
    int db = 0;
    for (int k0 = 0; k0 < D_; k0 += 32) {
        __syncthreads();
        if (k0 + 32 < D_) stage(db ^ 1, k0 + 32);

        bf16x8 af[2], bfr[4];
#pragma unroll
        for (int mt = 0; mt < 2; mt++)
            af[mt] = *(const bf16x8*)&Ast[db][wm + mt * 16 + l16][quad * 8];
#pragma unroll
        for (int nt = 0; nt < 4; nt++)
            bfr[nt] = *(const bf16x8*)&Bst[db][wn + nt * 16 + l16][quad * 8];
#pragma unroll
        for (int mt = 0; mt < 2; mt++)
#pragma unroll
            for (int nt = 0; nt < 4; nt++)
                acc[mt][nt] = __builtin_amdgcn_mfma_f32_16x16x32_bf16(
                    af[mt], bfr[nt], acc[mt][nt], 0, 0, 0);
        db ^= 1;
    }

#pragma unroll
    for (int mt = 0; mt < 2; mt++)
#pragma unroll
        for (int nt = 0; nt < 4; nt++)
#pragma unroll
            for (int reg = 0; reg < 4; reg++) {
                int row = row0 + wm + mt * 16 + quad * 4 + reg;
                int col = col0 + wn + nt * 16 + l16;
                out[(size_t)row * D_ + col] = acc[mt][nt][reg];
            }
}

// ---------------------------------------------------------------------------
// MFMA flash attention (round-8 counted-vmcnt base). THIS ROUND: cut the
// issue count of the softmax chain (attn is issue-bound: VALUBusy ~50%,
// MfmaUtil ~13%, no pipe saturated):
//  (1) float4 bias window table tabW (1152 entries, q0-relative — the
//      round-7-proven window pattern): the 4 per-t scalar bias gathers
//      become ONE aligned ds_read_b128 (lane stride 16B = conflict-free).
//  (2) MFMA row-sums: lacc[sub] = mfma(pf, ones, lacc) accumulates
//      sum_k P[q][k] in EXACTLY O's lane layout (row = quad*4+reg) —
//      deletes 7 VALU adds per block AND the epilogue shuffle chain
//      (inv = 1/lacc[sub][reg] elementwise).  VALU work -> MFMA pipe,
//      which is 87% idle.
// LDS: 3-buf K/V 49.2K + tabW 18.4K = 67.6 KB -> still 2 blocks/CU.
// Staging / counted-vmcnt sync structure byte-identical to round 8.
// ---------------------------------------------------------------------------
__global__ __launch_bounds__(256) void attn_mfma(
    const unsigned short* __restrict__ Qb, const unsigned short* __restrict__ Kb,
    const unsigned short* __restrict__ Vtb, const float* __restrict__ rel_emb,
    unsigned short* __restrict__ CTXb)
{
    __shared__ __align__(16) unsigned short Ks[3][64][64];   // [buf][kc][d]  128B rows
    __shared__ __align__(16) unsigned short Vts[3][64][64];  // [buf][d][kc]  128B rows
    __shared__ __align__(16) float4 tabW[1152];              // bias windows

    const int bid = blockIdx.x;
    const int bh = bid & 63;          // (b,h): XCD residue = bh%8
    const int b = bh >> 4, h = bh & 15;
    const int q0 = (bid >> 6) * 128;
    const int tid = threadIdx.x;
    const int wave = tid >> 6, lane = tid & 63;
    const int quad = lane >> 4, l16 = lane & 15;
    const int qw = q0 + wave * 32;

    // tabW[i] = {bias(i-off), bias(i-off+1), bias(i-off+2), bias(i-off+3)},
    // off = q0+127; in-loop index = rel + off with q0 cancelling.
    for (int i = tid; i < 1152; i += 256) {
        float4 v;
#pragma unroll
        for (int j = 0; j < 4; j++) {
            int rel = i - (q0 + 127) + j;  // k - q
            int n = -rel, ret = 0;
            if (n < 0) { ret = 16; n = -n; }
            int bkt;
            if (n < 8) bkt = ret + n;
            else {
                float t = logf((float)n / 8.0f) / logf(16.0f) * 8.0f;
                int vv = 8 + (int)t;
                if (vv > 15) vv = 15;
                bkt = ret + vv;
            }
            (&v.x)[j] = rel_emb[bkt * H_ + h] * LOG2E - BIAS_OFF;
        }
        tabW[i] = v;
    }

    const size_t hb = (size_t)(b * H_ + h) * (S_ * DK_);
    const unsigned short* Qp = Qb + hb;
    const unsigned short* Kp = Kb + hb;
    const unsigned short* Vp = Vtb + hb;

    bf16x8 qf[2][2];
#pragma unroll
    for (int sub = 0; sub < 2; sub++)
#pragma unroll
        for (int ks = 0; ks < 2; ks++)
            qf[sub][ks] = *(const bf16x8*)
                &Qp[(size_t)(qw + sub * 16 + l16) * DK_ + ks * 32 + quad * 8];

    // ones operand for MFMA row-sums
    bf16x8 onesf;
#pragma unroll
    for (int j = 0; j < 8; j++) onesf[j] = (short)0x3F80;

    f32x4 O[2][4];
#pragma unroll
    for (int sub = 0; sub < 2; sub++)
#pragma unroll
        for (int dt = 0; dt < 4; dt++) O[sub][dt] = 0;
    f32x4 lacc[2];
    lacc[0] = 0; lacc[1] = 0;     // row-sums, same lane layout as O

    const int swz = l16 & 7;          // read-side XOR key
    const int kr8 = lane >> 3;        // row-in-8-block
    const int kck = ((lane & 7) ^ kr8) * 8;  // inverse-swizzled src col (shorts)

    // stage one 64-wide K/V chunk into buffer sb (4 gl2lds per wave).
    auto stageKV = [&](int sb, int kg) {
#pragma unroll
        for (int i = 0; i < 2; i++) {
            int blk = wave * 2 + i;   // 0..7
            gl2lds16(&Kp[(size_t)(kg + blk * 8 + kr8) * DK_ + kck],
                     &Ks[sb][blk * 8][0]);
            gl2lds16(&Vp[(size_t)(blk * 8 + kr8) * S_ + kg + kck],
                     &Vts[sb][blk * 8][0]);
        }
    };

    // prologue: 2 chunks in flight
    stageKV(0, 0);
    stageKV(1, 64);

    const int qoff = 127 - (wave * 32 + l16);   // table base, lane-constant

    for (int kt = 0; kt < 16; kt++) {
        const int k0 = kt * 64;
        const int db = kt % 3;
        // counted wait: chunk kt retired, chunk kt+1 stays in flight across
        // the barrier; lgkmcnt(0) so all reads of chunk kt-1 (and the tabW
        // writes, at kt=0) are drained before buffers are (re)used.
        if (kt < 15) asm volatile("s_waitcnt vmcnt(4) lgkmcnt(0)" ::: "memory");
        else         asm volatile("s_waitcnt vmcnt(0) lgkmcnt(0)" ::: "memory");
        __builtin_amdgcn_s_barrier();
        __builtin_amdgcn_sched_barrier(0);
        if (kt < 14) stageKV((kt + 2) % 3, k0 + 128);   // 2-ahead prefetch

#pragma unroll
        for (int nt2 = 0; nt2 < 2; nt2++) {
            bf16x8 kf[2][2], vf[4];
#pragma unroll
            for (int t = 0; t < 2; t++) {
                int row = (2 * nt2 + t) * 16 + l16;
#pragma unroll
                for (int ks = 0; ks < 2; ks++)
                    kf[t][ks] = *(const bf16x8*)
                        &Ks[db][row][((ks * 4 + quad) ^ swz) * 8];
            }
#pragma unroll
            for (int dt = 0; dt < 4; dt++)
                vf[dt] = *(const bf16x8*)
                    &Vts[db][dt * 16 + l16][((nt2 * 4 + quad) ^ swz) * 8];

#pragma unroll
            for (int sub = 0; sub < 2; sub++) {
                // S^T tile: C[row = k_local = quad*4+reg][col = q = l16]
                // bias init: one ds_read_b128 per t (window table)
                f32x4 sacc[2];
#pragma unroll
                for (int t = 0; t < 2; t++) {
                    int iw = qoff + k0 + (2 * nt2 + t) * 16 + quad * 4
                             - sub * 16;
                    float4 bl = tabW[iw];
                    sacc[t][0] = bl.x; sacc[t][1] = bl.y;
                    sacc[t][2] = bl.z; sacc[t][3] = bl.w;
                }
                __builtin_amdgcn_s_setprio(1);
#pragma unroll
                for (int ks = 0; ks < 2; ks++)
#pragma unroll
                    for (int t = 0; t < 2; t++)
                        sacc[t] = __builtin_amdgcn_mfma_f32_16x16x32_bf16(
                            kf[t][ks], qf[sub][ks], sacc[t], 0, 0, 0);
                __builtin_amdgcn_s_setprio(0);

                // P = exp2(S^T); each lane: q = l16, k = quad*4+reg (+16t)
                float e0[4], e1[4];
#pragma unroll
                for (int reg = 0; reg < 4; reg++) {
                    e0[reg] = exp2_fast(sacc[0][reg]);
                    e1[reg] = exp2_fast(sacc[1][reg]);
                }

                // pack to bf16 pairs: x0,x1 = t0 (k 0..3), x2,x3 = t1 (k 16..19..)
                int x0 = cvt_pk_bf16(e0[0], e0[1]);
                int x1 = cvt_pk_bf16(e0[2], e0[3]);
                int x2 = cvt_pk_bf16(e1[0], e1[1]);
                int x3 = cvt_pk_bf16(e1[2], e1[3]);
                // quad-transpose: after these 4 swaps lane quad q holds
                // dwords covering k = q*8 .. q*8+7 of this 32-k block.
                asm("v_permlane32_swap_b32 %0, %1" : "+v"(x0), "+v"(x2));
                asm("v_permlane32_swap_b32 %0, %1" : "+v"(x1), "+v"(x3));
                asm("v_permlane16_swap_b32 %0, %1" : "+v"(x0), "+v"(x2));
                asm("v_permlane16_swap_b32 %0, %1" : "+v"(x1), "+v"(x3));
                int4 pi; pi.x = x0; pi.y = x1; pi.z = x2; pi.w = x3;
                bf16x8 pf = __builtin_bit_cast(bf16x8, pi);

                __builtin_amdgcn_s_setprio(1);
#pragma unroll
                for (int dt = 0; dt < 4; dt++)
                    O[sub][dt] = __builtin_amdgcn_mfma_f32_16x16x32_bf16(
                        pf, vf[dt], O[sub][dt], 0, 0, 0);
                // row-sum via ones-vector: lands in O's lane layout
                lacc[sub] = __builtin_amdgcn_mfma_f32_16x16x32_bf16(
                    pf, onesf, lacc[sub], 0, 0, 0);
                __builtin_amdgcn_s_setprio(0);
            }
        }
    }

    // epilogue: inv is elementwise-aligned with O (row = quad*4+reg) —
    // no cross-lane reduction needed at all.
#pragma unroll
    for (int sub = 0; sub < 2; sub++)
#pragma unroll
        for (int reg = 0; reg < 4; reg++) {
            float inv = 1.0f / lacc[sub][reg];
            int s = qw + sub * 16 + quad * 4 + reg;
#pragma unroll
            for (int dt = 0; dt < 4; dt++) {
                int col = h * DK_ + dt * 16 + l16;
                CTXb[((size_t)(b * S_ + s)) * D_ + col] = f2bf(O[sub][dt][reg] * inv);
            }
        }
}

// ---------------------------------------------------------------------------
extern "C" void kernel_launch(void* const* d_in, const int* in_sizes, int n_in,
                              void* d_out, int out_size, void* d_ws, size_t ws_size,
                              hipStream_t stream) {
    const float* x   = (const float*)d_in[0];
    const float* Wq  = (const float*)d_in[1];
    const float* Wk  = (const float*)d_in[2];
    const float* Wv  = (const float*)d_in[3];
    const float* Wo  = (const float*)d_in[4];
    const float* rel = (const float*)d_in[5];
    float* out = (float*)d_out;

    unsigned short* ws = (unsigned short*)d_ws;
    unsigned short* xb   = ws;                       // 4194304
    unsigned short* Wts  = ws + (size_t)4194304;     // 4x1048576
    unsigned short* Qb   = ws + (size_t)8388608;
    unsigned short* Kb   = ws + (size_t)12582912;
    unsigned short* Vtb  = ws + (size_t)16777216;
    unsigned short* CTXb = ws + (size_t)20971520;

    conv_all<<<8192, 256, 0, stream>>>(x, Wq, Wk, Wv, Wo, xb, Wts);
    gemm_qkv<<<768, 256, 0, stream>>>(xb, Wts, Qb, Kb, Vtb);
    attn_mfma<<<512, 256, 0, stream>>>(Qb, Kb, Vtb, rel, CTXb);
    gemm_out<<<512, 256, 0, stream>>>(CTXb, Wts + (size_t)3 * 1048576, out);
}

// Round 10
// 167.080 us; speedup vs baseline: 1.0125x; 1.0125x over previous
//
#include <hip/hip_runtime.h>
#include <math.h>

#define B_ 4
#define S_ 1024
#define D_ 1024
#define H_ 16
#define DK_ 64

typedef short bf16x8 __attribute__((ext_vector_type(8)));
typedef float f32x4 __attribute__((ext_vector_type(4)));

__device__ __forceinline__ unsigned short f2bf(float f) {
    unsigned int u = __float_as_uint(f);
    u = (u + 0x7FFFu + ((u >> 16) & 1u)) >> 16;  // RNE
    return (unsigned short)u;
}

__device__ __forceinline__ float exp2_fast(float x) {
#if __has_builtin(__builtin_amdgcn_exp2f)
    return __builtin_amdgcn_exp2f(x);
#else
    return exp2f(x);
#endif
}

// single-instruction pack: lo -> bits[15:0], hi -> bits[31:16] (bf16 RNE)
__device__ __forceinline__ int cvt_pk_bf16(float lo, float hi) {
    int r;
    asm("v_cvt_pk_bf16_f32 %0, %1, %2" : "=v"(r) : "v"(lo), "v"(hi));
    return r;
}

// async 16B/lane global -> LDS (lands at lds_base + lane*16)
__device__ __forceinline__ void gl2lds16(const void* g, void* l) {
    typedef unsigned int u32;
    auto gp = (const __attribute__((address_space(1))) u32*)(unsigned long long)g;
    auto lp = (__attribute__((address_space(3))) u32*)(unsigned int)(unsigned long long)l;
    __builtin_amdgcn_global_load_lds(gp, lp, 16, 0, 0);
}

#define LOG2E 1.44269504f
#define BIAS_OFF 20.0f

// ---------------------------------------------------------------------------
// fused conversion kernel: blocks [0,4096) convert x -> bf16;
// blocks [4096,8192) transpose+convert the 4 weight matrices -> Wts
// ---------------------------------------------------------------------------
__global__ __launch_bounds__(256) void conv_all(
    const float* __restrict__ x,
    const float* __restrict__ W0, const float* __restrict__ W1,
    const float* __restrict__ W2, const float* __restrict__ W3,
    unsigned short* __restrict__ xb, unsigned short* __restrict__ Wts)
{
    __shared__ float T[32][33];
    const int t = threadIdx.x;
    const int bid = blockIdx.x;

    if (bid < 4096) {
        int i = (bid * 256 + t) * 4;
        float4 v = *(const float4*)&x[i];
        ushort4 o;
        o.x = f2bf(v.x); o.y = f2bf(v.y); o.z = f2bf(v.z); o.w = f2bf(v.w);
        *(ushort4*)&xb[i] = o;
        return;
    }
    int tile = bid - 4096;
    const int mat = tile >> 10;
    tile &= 1023;
    const float* W = (mat == 0) ? W0 : (mat == 1) ? W1 : (mat == 2) ? W2 : W3;
    unsigned short* Wt = Wts + (size_t)mat * 1048576;
    const int k0 = (tile >> 5) * 32, n0 = (tile & 31) * 32;
    {
        int r = t >> 3, c4 = (t & 7) * 4;
        float4 v = *(const float4*)&W[(size_t)(k0 + r) * D_ + n0 + c4];
        T[r][c4 + 0] = v.x; T[r][c4 + 1] = v.y; T[r][c4 + 2] = v.z; T[r][c4 + 3] = v.w;
    }
    __syncthreads();
    {
        int rn = t >> 3, c4 = (t & 7) * 4;
        ushort4 o;
        o.x = f2bf(T[c4 + 0][rn]); o.y = f2bf(T[c4 + 1][rn]);
        o.z = f2bf(T[c4 + 2][rn]); o.w = f2bf(T[c4 + 3][rn]);
        *(ushort4*)&Wt[(size_t)(n0 + rn) * D_ + k0 + c4] = o;
    }
}

// ---------------------------------------------------------------------------
// bf16 MFMA GEMM 128x128, BK=32. Double-buffered LDS with single barrier
// per K-step: issue next K-step's global_load_lds right after the barrier,
// compute current buffer. LDS 32 KB; grid 768 = 3/CU, XCD-swizzled.
// ---------------------------------------------------------------------------
__global__ __launch_bounds__(256) void gemm_qkv(
    const unsigned short* __restrict__ xb,
    const unsigned short* __restrict__ Wts,
    unsigned short* __restrict__ Qb, unsigned short* __restrict__ Kb,
    unsigned short* __restrict__ Vtb)
{
    const int bid = blockIdx.x;
    const int by = bid & 31;          // x row-tile: XCD residue = by%8
    const int t_ = bid >> 5;          // 0..23
    const int z = t_ >> 3;            // 0..2 (Wq/Wk/Wv)
    const int bx = t_ & 7;            // W col-tile
    const unsigned short* Bt = Wts + (size_t)z * 1048576;

    __shared__ __align__(16) unsigned short Ast[2][128][32];
    __shared__ __align__(16) unsigned short Bst[2][128][32];

    const int tid = threadIdx.x;
    const int wave = tid >> 6, lane = tid & 63;
    const int quad = lane >> 4, l16 = lane & 15;
    const int wm = (wave & 1) * 64, wn = (wave >> 1) * 64;
    const int row0 = by * 128, col0 = bx * 128;
    const int lr = lane >> 2, lc = (lane & 3) * 8;

    f32x4 acc[4][4];
#pragma unroll
    for (int i = 0; i < 4; i++)
#pragma unroll
        for (int j = 0; j < 4; j++) acc[i][j] = 0;

    auto stage = [&](int sb, int k0) {
#pragma unroll
        for (int c = 0; c < 2; c++) {
            int m = wave * 32 + c * 16;
            gl2lds16(&xb[(size_t)(row0 + m + lr) * D_ + k0 + lc], &Ast[sb][m][0]);
            gl2lds16(&Bt[(size_t)(col0 + m + lr) * D_ + k0 + lc], &Bst[sb][m][0]);
        }
    };

    stage(0, 0);
    int db = 0;
    for (int k0 = 0; k0 < D_; k0 += 32) {
        // single barrier: drains this buffer's loads (issued one compute
        // phase ago for k0>0) and orders reuse of the other buffer.
        __syncthreads();
        if (k0 + 32 < D_) stage(db ^ 1, k0 + 32);

        bf16x8 af[4], bfr[4];
#pragma unroll
        for (int mt = 0; mt < 4; mt++)
            af[mt] = *(const bf16x8*)&Ast[db][wm + mt * 16 + l16][quad * 8];
#pragma unroll
        for (int nt = 0; nt < 4; nt++)
            bfr[nt] = *(const bf16x8*)&Bst[db][wn + nt * 16 + l16][quad * 8];
#pragma unroll
        for (int mt = 0; mt < 4; mt++)
#pragma unroll
            for (int nt = 0; nt < 4; nt++)
                acc[mt][nt] = __builtin_amdgcn_mfma_f32_16x16x32_bf16(
                    af[mt], bfr[nt], acc[mt][nt], 0, 0, 0);
        db ^= 1;
    }

    const float scale = (z == 0) ? LOG2E : 1.0f;
#pragma unroll
    for (int mt = 0; mt < 4; mt++)
#pragma unroll
        for (int nt = 0; nt < 4; nt++)
#pragma unroll
            for (int reg = 0; reg < 4; reg++) {
                int row = row0 + wm + mt * 16 + quad * 4 + reg;
                int col = col0 + wn + nt * 16 + l16;
                int b = row >> 10, s = row & 1023;
                int h = col >> 6, dk = col & 63;
                unsigned short v = f2bf(acc[mt][nt][reg] * scale);
                if (z == 0)      Qb[(((size_t)(b * H_ + h)) * S_ + s) * DK_ + dk] = v;
                else if (z == 1) Kb[(((size_t)(b * H_ + h)) * S_ + s) * DK_ + dk] = v;
                else             Vtb[(((size_t)(b * H_ + h)) * DK_ + dk) * S_ + s] = v;
            }
}

// ---------------------------------------------------------------------------
// Output GEMM: 64x128 tile, BK=32, double-buffered single-barrier prefetch.
// Flat grid 512, XCD-swizzled (bid%8==by%8).
// ---------------------------------------------------------------------------
__global__ __launch_bounds__(256) void gemm_out(
    const unsigned short* __restrict__ Ab,
    const unsigned short* __restrict__ Bt,
    float* __restrict__ out)
{
    const int bid = blockIdx.x;
    const int by = bid & 63;          // A row-tile: XCD residue = by%8
    const int bx = bid >> 6;          // 0..7

    __shared__ __align__(16) unsigned short Ast[2][64][32];
    __shared__ __align__(16) unsigned short Bst[2][128][32];

    const int tid = threadIdx.x;
    const int wave = tid >> 6, lane = tid & 63;
    const int quad = lane >> 4, l16 = lane & 15;
    const int wm = (wave & 1) * 32, wn = (wave >> 1) * 64;
    const int row0 = by * 64, col0 = bx * 128;
    const int lr = lane >> 2, lc = (lane & 3) * 8;

    f32x4 acc[2][4];
#pragma unroll
    for (int i = 0; i < 2; i++)
#pragma unroll
        for (int j = 0; j < 4; j++) acc[i][j] = 0;

    auto stage = [&](int sb, int k0) {
        gl2lds16(&Ab[(size_t)(row0 + wave * 16 + lr) * D_ + k0 + lc],
                 &Ast[sb][wave * 16][0]);
#pragma unroll
        for (int c = 0; c < 2; c++) {
            int m = (wave * 2 + c) * 16;
            gl2lds16(&Bt[(size_t)(col0 + m + lr) * D_ + k0 + lc], &Bst[sb][m][0]);
        }
    };

    stage(0, 0);
    int db = 0;
    for (int k0 = 0; k0 < D_; k0 += 32) {
        __syncthreads();
        if (k0 + 32 < D_) stage(db ^ 1, k0 + 32);

        bf16x8 af[2], bfr[4];
#pragma unroll
        for (int mt = 0; mt < 2; mt++)
            af[mt] = *(const bf16x8*)&Ast[db][wm + mt * 16 + l16][quad * 8];
#pragma unroll
        for (int nt = 0; nt < 4; nt++)
            bfr[nt] = *(const bf16x8*)&Bst[db][wn + nt * 16 + l16][quad * 8];
#pragma unroll
        for (int mt = 0; mt < 2; mt++)
#pragma unroll
            for (int nt = 0; nt < 4; nt++)
                acc[mt][nt] = __builtin_amdgcn_mfma_f32_16x16x32_bf16(
                    af[mt], bfr[nt], acc[mt][nt], 0, 0, 0);
        db ^= 1;
    }

#pragma unroll
    for (int mt = 0; mt < 2; mt++)
#pragma unroll
        for (int nt = 0; nt < 4; nt++)
#pragma unroll
            for (int reg = 0; reg < 4; reg++) {
                int row = row0 + wm + mt * 16 + quad * 4 + reg;
                int col = col0 + wn + nt * 16 + l16;
                out[(size_t)row * D_ + col] = acc[mt][nt][reg];
            }
}

// ---------------------------------------------------------------------------
// MFMA flash attention. THIS ROUND: q-tile 64 -> grid 1024 -> 4 blocks/CU.
// Round 9's null (VALU cut, no change) + round 8's near-null (counted
// vmcnt) prove the kernel is chain-LATENCY-bound at 2 waves/SIMD; the
// only remaining lever is TLP.  Round 5's failure was re-audited: the bug
// was its V-staging geometry (4-row blocks vs 1024B writes), NOT the
// q-tile-64 restructure; round 6 fixed staging (8-row x 128B blocks) and
// this kernel keeps that staging byte-identical.  Single sub per wave
// (qw = q0 + wave*16), scalar 1087-entry bias window (q0 cancels in the
// in-loop index), ones-MFMA row-sums + shuffle-free epilogue (round 9).
// LDS: 2-buf K/V 32 KB + 4.3 KB table = 36.2 KB -> 4 blocks/CU; grid
// 1024 = 256 CU x 4.  XCD swizzle: bid%8 == bh%8.
// ---------------------------------------------------------------------------
__global__ __launch_bounds__(256) void attn_mfma(
    const unsigned short* __restrict__ Qb, const unsigned short* __restrict__ Kb,
    const unsigned short* __restrict__ Vtb, const float* __restrict__ rel_emb,
    unsigned short* __restrict__ CTXb)
{
    __shared__ __align__(16) unsigned short Ks[2][64][64];   // [buf][kc][d]  128B rows
    __shared__ __align__(16) unsigned short Vts[2][64][64];  // [buf][d][kc]  128B rows
    __shared__ float bias_tab[1087];

    const int bid = blockIdx.x;
    const int bh = bid & 63;          // (b,h): XCD residue = bh%8
    const int b = bh >> 4, h = bh & 15;
    const int q0 = (bid >> 6) * 64;   // 16 q-tiles of 64 rows
    const int tid = threadIdx.x;
    const int wave = tid >> 6, lane = tid & 63;
    const int quad = lane >> 4, l16 = lane & 15;
    const int qw = q0 + wave * 16;    // this wave's 16 q-rows

    // bias_tab[idx] = bias(rel = idx - 63 - q0), idx in [0,1087)
    for (int idx = tid; idx < 1087; idx += 256) {
        int rel = idx - 63 - q0;      // k - q
        int n = -rel, ret = 0;
        if (n < 0) { ret = 16; n = -n; }
        int bkt;
        if (n < 8) bkt = ret + n;
        else {
            float t = logf((float)n / 8.0f) / logf(16.0f) * 8.0f;
            int v = 8 + (int)t;
            if (v > 15) v = 15;
            bkt = ret + v;
        }
        bias_tab[idx] = rel_emb[bkt * H_ + h] * LOG2E - BIAS_OFF;
    }

    const size_t hb = (size_t)(b * H_ + h) * (S_ * DK_);
    const unsigned short* Qp = Qb + hb;
    const unsigned short* Kp = Kb + hb;
    const unsigned short* Vp = Vtb + hb;

    bf16x8 qf[2];
#pragma unroll
    for (int ks = 0; ks < 2; ks++)
        qf[ks] = *(const bf16x8*)&Qp[(size_t)(qw + l16) * DK_ + ks * 32 + quad * 8];

    // ones operand for MFMA row-sums
    bf16x8 onesf;
#pragma unroll
    for (int j = 0; j < 8; j++) onesf[j] = (short)0x3F80;

    f32x4 O[4];
#pragma unroll
    for (int dt = 0; dt < 4; dt++) O[dt] = 0;
    f32x4 lacc;
    lacc = 0;                         // row-sums, same lane layout as O

    const int swz = l16 & 7;          // read-side XOR key
    const int kr8 = lane >> 3;        // row-in-8-block
    const int kck = ((lane & 7) ^ kr8) * 8;  // inverse-swizzled src col (shorts)

    // stage one 64-wide K/V chunk into buffer sb: 8-row x 128B blocks,
    // linear LDS dest + inverse-swizzled global source (read XORs back).
    // Byte-identical to the round-6-verified staging.
    auto stageKV = [&](int sb, int kg) {
#pragma unroll
        for (int i = 0; i < 2; i++) {
            int blk = wave * 2 + i;   // 0..7
            gl2lds16(&Kp[(size_t)(kg + blk * 8 + kr8) * DK_ + kck],
                     &Ks[sb][blk * 8][0]);
            gl2lds16(&Vp[(size_t)(blk * 8 + kr8) * S_ + kg + kck],
                     &Vts[sb][blk * 8][0]);
        }
    };

    stageKV(0, 0);   // prologue: issue chunk 0

    for (int kt = 0; kt < 16; kt++) {
        const int k0 = kt * 64;
        const int db = kt & 1;
        // single barrier: drains current buffer's loads (issued one full
        // compute phase ago for kt>0) and orders the buf^1 reuse; also
        // orders the bias_tab writes at kt=0.
        __syncthreads();
        if (kt < 15) stageKV(db ^ 1, k0 + 64);   // prefetch next chunk

#pragma unroll
        for (int nt2 = 0; nt2 < 2; nt2++) {
            bf16x8 kf[2][2], vf[4];
#pragma unroll
            for (int t = 0; t < 2; t++) {
                int row = (2 * nt2 + t) * 16 + l16;
#pragma unroll
                for (int ks = 0; ks < 2; ks++)
                    kf[t][ks] = *(const bf16x8*)
                        &Ks[db][row][((ks * 4 + quad) ^ swz) * 8];
            }
#pragma unroll
            for (int dt = 0; dt < 4; dt++)
                vf[dt] = *(const bf16x8*)
                    &Vts[db][dt * 16 + l16][((nt2 * 4 + quad) ^ swz) * 8];

            // S^T tile: C[row = k_local = quad*4+reg][col = q = l16]
            // bias idx = (k - q) + 63 + q0; q0 cancels:
            // b0 = 63 + k0 + (2nt2+t)*16 + quad*4 - wave*16 - l16
            f32x4 sacc[2];
#pragma unroll
            for (int t = 0; t < 2; t++) {
                int b0 = 63 + k0 + (2 * nt2 + t) * 16 + quad * 4
                         - wave * 16 - l16;
#pragma unroll
                for (int reg = 0; reg < 4; reg++)
                    sacc[t][reg] = bias_tab[b0 + reg];
            }
            __builtin_amdgcn_s_setprio(1);
#pragma unroll
            for (int ks = 0; ks < 2; ks++)
#pragma unroll
                for (int t = 0; t < 2; t++)
                    sacc[t] = __builtin_amdgcn_mfma_f32_16x16x32_bf16(
                        kf[t][ks], qf[ks], sacc[t], 0, 0, 0);
            __builtin_amdgcn_s_setprio(0);

            // P = exp2(S^T); each lane: q = l16, k = quad*4+reg (+16t)
            float e0[4], e1[4];
#pragma unroll
            for (int reg = 0; reg < 4; reg++) {
                e0[reg] = exp2_fast(sacc[0][reg]);
                e1[reg] = exp2_fast(sacc[1][reg]);
            }

            // pack to bf16 pairs: x0,x1 = t0 (k 0..3), x2,x3 = t1 (k 16..19..)
            int x0 = cvt_pk_bf16(e0[0], e0[1]);
            int x1 = cvt_pk_bf16(e0[2], e0[3]);
            int x2 = cvt_pk_bf16(e1[0], e1[1]);
            int x3 = cvt_pk_bf16(e1[2], e1[3]);
            // quad-transpose: after these 4 swaps lane quad q holds
            // dwords covering k = q*8 .. q*8+7 of this 32-k block.
            asm("v_permlane32_swap_b32 %0, %1" : "+v"(x0), "+v"(x2));
            asm("v_permlane32_swap_b32 %0, %1" : "+v"(x1), "+v"(x3));
            asm("v_permlane16_swap_b32 %0, %1" : "+v"(x0), "+v"(x2));
            asm("v_permlane16_swap_b32 %0, %1" : "+v"(x1), "+v"(x3));
            int4 pi; pi.x = x0; pi.y = x1; pi.z = x2; pi.w = x3;
            bf16x8 pf = __builtin_bit_cast(bf16x8, pi);

            __builtin_amdgcn_s_setprio(1);
#pragma unroll
            for (int dt = 0; dt < 4; dt++)
                O[dt] = __builtin_amdgcn_mfma_f32_16x16x32_bf16(
                    pf, vf[dt], O[dt], 0, 0, 0);
            // row-sum via ones-vector: lands in O's lane layout
            lacc = __builtin_amdgcn_mfma_f32_16x16x32_bf16(
                pf, onesf, lacc, 0, 0, 0);
            __builtin_amdgcn_s_setprio(0);
        }
    }

    // epilogue: inv is elementwise-aligned with O (row = quad*4+reg) —
    // no cross-lane reduction needed.
#pragma unroll
    for (int reg = 0; reg < 4; reg++) {
        float inv = 1.0f / lacc[reg];
        int s = qw + quad * 4 + reg;
#pragma unroll
        for (int dt = 0; dt < 4; dt++) {
            int col = h * DK_ + dt * 16 + l16;
            CTXb[((size_t)(b * S_ + s)) * D_ + col] = f2bf(O[dt][reg] * inv);
        }
    }
}

// ---------------------------------------------------------------------------
extern "C" void kernel_launch(void* const* d_in, const int* in_sizes, int n_in,
                              void* d_out, int out_size, void* d_ws, size_t ws_size,
                              hipStream_t stream) {
    const float* x   = (const float*)d_in[0];
    const float* Wq  = (const float*)d_in[1];
    const float* Wk  = (const float*)d_in[2];
    const float* Wv  = (const float*)d_in[3];
    const float* Wo  = (const float*)d_in[4];
    const float* rel = (const float*)d_in[5];
    float* out = (float*)d_out;

    unsigned short* ws = (unsigned short*)d_ws;
    unsigned short* xb   = ws;                       // 4194304
    unsigned short* Wts  = ws + (size_t)4194304;     // 4x1048576
    unsigned short* Qb   = ws + (size_t)8388608;
    unsigned short* Kb   = ws + (size_t)12582912;
    unsigned short* Vtb  = ws + (size_t)16777216;
    unsigned short* CTXb = ws + (size_t)20971520;

    conv_all<<<8192, 256, 0, stream>>>(x, Wq, Wk, Wv, Wo, xb, Wts);
    gemm_qkv<<<768, 256, 0, stream>>>(xb, Wts, Qb, Kb, Vtb);
    attn_mfma<<<1024, 256, 0, stream>>>(Qb, Kb, Vtb, rel, CTXb);
    gemm_out<<<512, 256, 0, stream>>>(CTXb, Wts + (size_t)3 * 1048576, out);
}